// Round 6
// baseline (231.380 us; speedup 1.0000x reference)
//
#include <hip/hip_runtime.h>

#define HW 16384
#define C 128

typedef __attribute__((ext_vector_type(8))) short short8;
typedef __attribute__((ext_vector_type(4))) float f32x4;

__device__ __forceinline__ unsigned short f2bf(float f) {
  union { float f; unsigned u; } v; v.f = f;
  return (unsigned short)((v.u + 0x7fffu + ((v.u >> 16) & 1u)) >> 16);
}
__device__ __forceinline__ float bflo(unsigned w) {
  union { unsigned u; float f; } v; v.u = w << 16; return v.f;
}
__device__ __forceinline__ float bfhi(unsigned w) {
  union { unsigned u; float f; } v; v.u = w & 0xffff0000u; return v.f;
}
__device__ __forceinline__ unsigned long long pk4(float a, float b, float c, float d) {
  return (unsigned long long)f2bf(a) | ((unsigned long long)f2bf(b) << 16) |
         ((unsigned long long)f2bf(c) << 32) | ((unsigned long long)f2bf(d) << 48);
}

// ---------------- Kernel 0: precompute bilinear weight table ------------------
__global__ void k_prep(const float* __restrict__ delta, float* __restrict__ pw,
                       int* __restrict__ pi) {
  int k = threadIdx.x;
  if (k < 8) {
    float s0 = tanhf(delta[k * 2 + 0]) * 4.0f;  // col shift (x)
    float s1 = tanhf(delta[k * 2 + 1]) * 4.0f;  // row shift (y)
    float f0 = floorf(s0), f1 = floorf(s1);
    pi[2 * k + 0] = (int)f0;
    pi[2 * k + 1] = (int)f1;
    float fx = s0 - f0, fy = s1 - f1;
    pw[4 * k + 0] = (1.0f - fx) * (1.0f - fy);
    pw[4 * k + 1] = fx * (1.0f - fy);
    pw[4 * k + 2] = (1.0f - fx) * fy;
    pw[4 * k + 3] = fx * fy;
  }
}

// ---------------- Kernel 1: qkv = w_qkv @ x  (bf16 MFMA) ----------------------
// q,k,v -> separate [pix][ch] bf16 buffers (k,v split so each gather phase has
// a 4 MB/batch working set that fits one XCD's L2).
__global__ __launch_bounds__(256) void k_qkv(const float* __restrict__ x,
                                             const float* __restrict__ w_qkv,
                                             unsigned short* __restrict__ qb,
                                             unsigned short* __restrict__ kb,
                                             unsigned short* __restrict__ vb) {
  __shared__ __align__(16) unsigned short Xs[128 * 128];
  __shared__ __align__(16) unsigned short Ws[128 * 128];
  const int t = threadIdx.x;
  const int gpix0 = blockIdx.x * 128;
  const int b = gpix0 >> 14;
  const int hw0 = gpix0 & (HW - 1);
  const int och0 = blockIdx.y * 128;

  const float* xb = x + (size_t)b * C * HW + hw0;
  #pragma unroll
  for (int i = 0; i < 16; ++i) {
    int linear = i * 256 + t;
    int p = linear & 127;
    int c4 = (linear >> 7) * 4;
    float a0 = xb[(size_t)(c4 + 0) * HW + p];
    float a1 = xb[(size_t)(c4 + 1) * HW + p];
    float a2 = xb[(size_t)(c4 + 2) * HW + p];
    float a3 = xb[(size_t)(c4 + 3) * HW + p];
    int cc = c4 ^ ((p & 7) << 3);
    *(unsigned long long*)&Xs[p * 128 + cc] = pk4(a0, a1, a2, a3);
  }
  const float* wb = w_qkv + (size_t)och0 * C;
  #pragma unroll
  for (int i = 0; i < 16; ++i) {
    int linear = i * 256 + t;
    int c4 = (linear & 31) * 4;
    int o = linear >> 5;
    float4 w4 = *(const float4*)(wb + (size_t)o * C + c4);
    int cc = c4 ^ ((o & 7) << 3);
    *(unsigned long long*)&Ws[o * 128 + cc] = pk4(w4.x, w4.y, w4.z, w4.w);
  }
  __syncthreads();

  const int wave = t >> 6, lane = t & 63;
  const int wr = wave >> 1, wc = wave & 1;
  const int rsel = lane & 15, quad = lane >> 4;

  f32x4 acc[4][4];
  #pragma unroll
  for (int mi = 0; mi < 4; ++mi)
    #pragma unroll
    for (int ni = 0; ni < 4; ++ni) acc[mi][ni] = (f32x4){0.f, 0.f, 0.f, 0.f};

  #pragma unroll
  for (int ks = 0; ks < 4; ++ks) {
    const int koff = ks * 32 + quad * 8;
    short8 afr[4], bfr[4];
    #pragma unroll
    for (int mi = 0; mi < 4; ++mi) {
      int r = wr * 64 + mi * 16 + rsel;
      afr[mi] = *(const short8*)&Xs[r * 128 + (koff ^ ((r & 7) << 3))];
    }
    #pragma unroll
    for (int ni = 0; ni < 4; ++ni) {
      int r = wc * 64 + ni * 16 + rsel;
      bfr[ni] = *(const short8*)&Ws[r * 128 + (koff ^ ((r & 7) << 3))];
    }
    #pragma unroll
    for (int mi = 0; mi < 4; ++mi)
      #pragma unroll
      for (int ni = 0; ni < 4; ++ni)
        acc[mi][ni] = __builtin_amdgcn_mfma_f32_16x16x32_bf16(afr[mi], bfr[ni], acc[mi][ni], 0, 0, 0);
  }

  unsigned short* dst = (och0 == 0) ? qb : ((och0 == 128) ? kb : vb);
  #pragma unroll
  for (int mi = 0; mi < 4; ++mi)
    #pragma unroll
    for (int ni = 0; ni < 4; ++ni)
      #pragma unroll
      for (int r = 0; r < 4; ++r) {
        int pix = gpix0 + wr * 64 + mi * 16 + quad * 4 + r;
        int ch = wc * 64 + ni * 16 + rsel;
        dst[(size_t)pix * C + ch] = f2bf(acc[mi][ni][r]);
      }
}

// ---------------- Kernel 2a: k-gather + logits + softmax -> probs (fp32) ------
__global__ __launch_bounds__(256) void k_attnA(const unsigned short* __restrict__ qb,
                                               const unsigned short* __restrict__ kb,
                                               const int* __restrict__ psf,
                                               const float* __restrict__ pw,
                                               const int* __restrict__ pi,
                                               float* __restrict__ probs) {
  const int t = threadIdx.x;
  const int lane = t & 63;
  const int p = blockIdx.x;
  const int b = (p >> 1) & 3;                    // batch -> XCD pair
  const int j = ((p >> 3) << 1) | (p & 1);
  const int spix = __builtin_amdgcn_readfirstlane((b << 14) + (j << 2) + (t >> 6));

  const unsigned* q32 = (const unsigned*)qb;
  const unsigned* k32 = (const unsigned*)kb + (size_t)b * HW * 64;  // SGPR base

  const unsigned qp = q32[(size_t)spix * 64 + lane];
  const float qx = bflo(qp), qy = bfhi(qp);

  int anch[16];
  #pragma unroll
  for (int jj = 0; jj < 16; ++jj) anch[jj] = psf[(size_t)spix * 16 + jj];

  float dk[8];
  #pragma unroll
  for (int k = 0; k < 8; ++k) {
    const int x0 = anch[k * 2 + 0] + pi[2 * k + 0], x1 = x0 + 1;
    const int y0 = anch[k * 2 + 1] + pi[2 * k + 1], y1 = y0 + 1;
    float ksx = 0, ksy = 0;
    #pragma unroll
    for (int cn = 0; cn < 4; ++cn) {
      const int xi = (cn & 1) ? x1 : x0;
      const int yi = (cn & 2) ? y1 : y0;
      const bool valid = (xi >= 0) & (xi <= 127) & (yi >= 0) & (yi <= 127);
      const int xc = min(max(xi, 0), 127);
      const int yc = min(max(yi, 0), 127);
      const float wv = valid ? pw[k * 4 + cn] : 0.0f;
      const unsigned kk = k32[(size_t)(yc * 128 + xc) * 64 + lane];  // 256B/wave
      ksx += wv * bflo(kk); ksy += wv * bfhi(kk);
    }
    dk[k] = qx * ksx + qy * ksy;
  }
  #pragma unroll
  for (int off = 32; off > 0; off >>= 1) {
    #pragma unroll
    for (int k = 0; k < 8; ++k) dk[k] += __shfl_xor(dk[k], off);
  }
  float lg[8];
  float m = dk[0] * 0.08838834764831845f;
  #pragma unroll
  for (int k = 0; k < 8; ++k) { lg[k] = dk[k] * 0.08838834764831845f; m = fmaxf(m, lg[k]); }
  float e[8], den = 0.0f;
  #pragma unroll
  for (int k = 0; k < 8; ++k) { e[k] = __expf(lg[k] - m); den += e[k]; }
  const float inv = 1.0f / den;
  if (lane == 0) {
    float4 p0 = make_float4(e[0] * inv, e[1] * inv, e[2] * inv, e[3] * inv);
    float4 p1 = make_float4(e[4] * inv, e[5] * inv, e[6] * inv, e[7] * inv);
    *(float4*)&probs[(size_t)spix * 8 + 0] = p0;
    *(float4*)&probs[(size_t)spix * 8 + 4] = p1;
  }
}

// ---------------- Kernel 2b: v-gather weighted by probs -> ao (bf16) ----------
__global__ __launch_bounds__(256) void k_attnB(const unsigned short* __restrict__ vb,
                                               const int* __restrict__ psf,
                                               const float* __restrict__ pw,
                                               const int* __restrict__ pi,
                                               const float* __restrict__ probs,
                                               unsigned short* __restrict__ ao) {
  const int t = threadIdx.x;
  const int lane = t & 63;
  const int p = blockIdx.x;
  const int b = (p >> 1) & 3;                    // batch -> XCD pair
  const int j = ((p >> 3) << 1) | (p & 1);
  const int spix = __builtin_amdgcn_readfirstlane((b << 14) + (j << 2) + (t >> 6));

  const unsigned* v32 = (const unsigned*)vb + (size_t)b * HW * 64;  // SGPR base

  int anch[16];
  #pragma unroll
  for (int jj = 0; jj < 16; ++jj) anch[jj] = psf[(size_t)spix * 16 + jj];

  float ox = 0.0f, oy = 0.0f;
  #pragma unroll
  for (int k = 0; k < 8; ++k) {
    const float pk = probs[(size_t)spix * 8 + k];   // wave-uniform scalar load
    const int x0 = anch[k * 2 + 0] + pi[2 * k + 0], x1 = x0 + 1;
    const int y0 = anch[k * 2 + 1] + pi[2 * k + 1], y1 = y0 + 1;
    #pragma unroll
    for (int cn = 0; cn < 4; ++cn) {
      const int xi = (cn & 1) ? x1 : x0;
      const int yi = (cn & 2) ? y1 : y0;
      const bool valid = (xi >= 0) & (xi <= 127) & (yi >= 0) & (yi <= 127);
      const int xc = min(max(xi, 0), 127);
      const int yc = min(max(yi, 0), 127);
      const float wv = valid ? (pk * pw[k * 4 + cn]) : 0.0f;
      const unsigned vv = v32[(size_t)(yc * 128 + xc) * 64 + lane];  // 256B/wave
      ox += wv * bflo(vv); oy += wv * bfhi(vv);
    }
  }
  ((unsigned*)ao)[(size_t)spix * 64 + lane] = (unsigned)f2bf(ox) | ((unsigned)f2bf(oy) << 16);
}

// ---------------- Kernel 3: out = x + w_proj @ ao  (bf16 MFMA) ----------------
__global__ __launch_bounds__(256) void k_proj(const unsigned short* __restrict__ ao,
                                              const float* __restrict__ w_proj,
                                              const float* __restrict__ x,
                                              float* __restrict__ out) {
  __shared__ __align__(16) unsigned short As[128 * 128];
  __shared__ __align__(16) unsigned short Ws[128 * 128];
  const int t = threadIdx.x;
  const int gpix0 = blockIdx.x * 128;
  const int b = gpix0 >> 14;
  const int hw0 = gpix0 & (HW - 1);

  #pragma unroll
  for (int i = 0; i < 8; ++i) {
    int linear = i * 256 + t;
    int c8 = (linear & 15) * 8;
    int p = linear >> 4;
    uint4 v = *(const uint4*)(ao + (size_t)(gpix0 + p) * C + c8);
    *(uint4*)&As[p * 128 + (c8 ^ ((p & 7) << 3))] = v;
  }
  #pragma unroll
  for (int i = 0; i < 16; ++i) {
    int linear = i * 256 + t;
    int c4 = (linear & 31) * 4;
    int o = linear >> 5;
    float4 w4 = *(const float4*)(w_proj + (size_t)o * C + c4);
    *(unsigned long long*)&Ws[o * 128 + (c4 ^ ((o & 7) << 3))] = pk4(w4.x, w4.y, w4.z, w4.w);
  }
  __syncthreads();

  const int wave = t >> 6, lane = t & 63;
  const int wr = wave >> 1, wc = wave & 1;
  const int rsel = lane & 15, quad = lane >> 4;

  f32x4 acc[4][4];
  #pragma unroll
  for (int mi = 0; mi < 4; ++mi)
    #pragma unroll
    for (int ni = 0; ni < 4; ++ni) acc[mi][ni] = (f32x4){0.f, 0.f, 0.f, 0.f};

  #pragma unroll
  for (int ks = 0; ks < 4; ++ks) {
    const int koff = ks * 32 + quad * 8;
    short8 afr[4], bfr[4];
    #pragma unroll
    for (int mi = 0; mi < 4; ++mi) {
      int r = wr * 64 + mi * 16 + rsel;
      afr[mi] = *(const short8*)&Ws[r * 128 + (koff ^ ((r & 7) << 3))];
    }
    #pragma unroll
    for (int ni = 0; ni < 4; ++ni) {
      int r = wc * 64 + ni * 16 + rsel;
      bfr[ni] = *(const short8*)&As[r * 128 + (koff ^ ((r & 7) << 3))];
    }
    #pragma unroll
    for (int mi = 0; mi < 4; ++mi)
      #pragma unroll
      for (int ni = 0; ni < 4; ++ni)
        acc[mi][ni] = __builtin_amdgcn_mfma_f32_16x16x32_bf16(afr[mi], bfr[ni], acc[mi][ni], 0, 0, 0);
  }

  #pragma unroll
  for (int mi = 0; mi < 4; ++mi)
    #pragma unroll
    for (int ni = 0; ni < 4; ++ni)
      #pragma unroll
      for (int r = 0; r < 4; ++r) {
        int och = wr * 64 + mi * 16 + quad * 4 + r;
        int pixl = wc * 64 + ni * 16 + rsel;
        size_t addr = ((size_t)b * C + och) * HW + hw0 + pixl;
        out[addr] = x[addr] + acc[mi][ni][r];
      }
}

extern "C" void kernel_launch(void* const* d_in, const int* in_sizes, int n_in,
                              void* d_out, int out_size, void* d_ws, size_t ws_size,
                              hipStream_t stream) {
  const float* x      = (const float*)d_in[0];
  const int*   psf    = (const int*)d_in[1];
  const float* delta  = (const float*)d_in[2];
  const float* w_qkv  = (const float*)d_in[3];
  const float* w_proj = (const float*)d_in[4];
  float* out = (float*)d_out;

  const size_t N = (size_t)4 * HW * C;            // 8388608 elems
  unsigned short* qb = (unsigned short*)d_ws;     // 16 MB
  unsigned short* kb = qb + N;                    // 16 MB
  unsigned short* vb = kb + N;                    // 16 MB
  unsigned short* ao = vb + N;                    // 16 MB
  float* probs = (float*)(ao + N);                // 2 MB (65536*8 fp32)
  float* pw = probs + (size_t)4 * HW * 8;         // 32 floats
  int*   pi = (int*)(pw + 32);                    // 16 ints

  k_prep<<<1, 64, 0, stream>>>(delta, pw, pi);
  k_qkv<<<dim3(512, 3), 256, 0, stream>>>(x, w_qkv, qb, kb, vb);
  k_attnA<<<dim3(HW), 256, 0, stream>>>(qb, kb, psf, pw, pi, probs);
  k_attnB<<<dim3(HW), 256, 0, stream>>>(vb, psf, pw, pi, probs, ao);
  k_proj<<<dim3(512), 256, 0, stream>>>(ao, w_proj, x, out);
}

// Round 7
// 178.567 us; speedup vs baseline: 1.2958x; 1.2958x over previous
//
#include <hip/hip_runtime.h>

#define HW 16384
#define C 128

typedef __attribute__((ext_vector_type(8))) short short8;
typedef __attribute__((ext_vector_type(4))) float f32x4;
typedef __attribute__((ext_vector_type(2))) float f32x2;

__device__ __forceinline__ unsigned short f2bf(float f) {
  union { float f; unsigned u; } v; v.f = f;
  return (unsigned short)((v.u + 0x7fffu + ((v.u >> 16) & 1u)) >> 16);
}
__device__ __forceinline__ float bflo(unsigned w) {
  union { unsigned u; float f; } v; v.u = w << 16; return v.f;
}
__device__ __forceinline__ float bfhi(unsigned w) {
  union { unsigned u; float f; } v; v.u = w & 0xffff0000u; return v.f;
}
__device__ __forceinline__ unsigned long long pk4(float a, float b, float c, float d) {
  return (unsigned long long)f2bf(a) | ((unsigned long long)f2bf(b) << 16) |
         ((unsigned long long)f2bf(c) << 32) | ((unsigned long long)f2bf(d) << 48);
}

// ---------------- Kernel 0: precompute bilinear weight table ------------------
__global__ void k_prep(const float* __restrict__ delta, float* __restrict__ pw,
                       int* __restrict__ pi) {
  int k = threadIdx.x;
  if (k < 8) {
    float s0 = tanhf(delta[k * 2 + 0]) * 4.0f;  // col shift (x)
    float s1 = tanhf(delta[k * 2 + 1]) * 4.0f;  // row shift (y)
    float f0 = floorf(s0), f1 = floorf(s1);
    pi[2 * k + 0] = (int)f0;
    pi[2 * k + 1] = (int)f1;
    float fx = s0 - f0, fy = s1 - f1;
    pw[4 * k + 0] = (1.0f - fx) * (1.0f - fy);
    pw[4 * k + 1] = fx * (1.0f - fy);
    pw[4 * k + 2] = (1.0f - fx) * fy;
    pw[4 * k + 3] = fx * fy;
  }
}

// ---------------- Kernel 1: qkv GEMM ------------------------------------------
// y=0: q (layout A: D row=pix col=och) -> qb bf16 [pix][ch], coalesced ushort.
// y=1: k+v (layout B: D row=och col=pix), two MFMA phases, packed fp8
//      [k0,k1,v0,v1] per dword, LDS-transposed for coalesced dword stores.
__global__ __launch_bounds__(256) void k_qkv(const float* __restrict__ x,
                                             const float* __restrict__ w_qkv,
                                             unsigned short* __restrict__ qb,
                                             unsigned* __restrict__ kvb) {
  __shared__ __align__(16) unsigned char smem[65536];
  unsigned short* Xs = (unsigned short*)smem;            // [pix][k] 32 KB
  unsigned short* Ws = (unsigned short*)(smem + 32768);  // [och][k] 32 KB
  const int t = threadIdx.x;
  const int gpix0 = blockIdx.x * 128;
  const int b = gpix0 >> 14;
  const int hw0 = gpix0 & (HW - 1);

  // stage Xs [pix][k] bf16, xor-swizzled
  const float* xb = x + (size_t)b * C * HW + hw0;
  #pragma unroll
  for (int i = 0; i < 16; ++i) {
    int linear = i * 256 + t;
    int p = linear & 127;
    int c4 = (linear >> 7) * 4;
    float a0 = xb[(size_t)(c4 + 0) * HW + p];
    float a1 = xb[(size_t)(c4 + 1) * HW + p];
    float a2 = xb[(size_t)(c4 + 2) * HW + p];
    float a3 = xb[(size_t)(c4 + 3) * HW + p];
    int cc = c4 ^ ((p & 7) << 3);
    *(unsigned long long*)&Xs[p * 128 + cc] = pk4(a0, a1, a2, a3);
  }

  const int wave = t >> 6, lane = t & 63;
  const int wr = wave >> 1, wc = wave & 1;
  const int rsel = lane & 15, quad = lane >> 4;

  if (blockIdx.y == 0) {
    // ---- q: layout A ----
    #pragma unroll
    for (int i = 0; i < 16; ++i) {
      int linear = i * 256 + t;
      int c4 = (linear & 31) * 4;
      int o = linear >> 5;
      float4 w4 = *(const float4*)(w_qkv + (size_t)o * C + c4);
      *(unsigned long long*)&Ws[o * 128 + (c4 ^ ((o & 7) << 3))] = pk4(w4.x, w4.y, w4.z, w4.w);
    }
    __syncthreads();
    f32x4 acc[4][4];
    #pragma unroll
    for (int mi = 0; mi < 4; ++mi)
      #pragma unroll
      for (int ni = 0; ni < 4; ++ni) acc[mi][ni] = (f32x4){0.f, 0.f, 0.f, 0.f};
    #pragma unroll
    for (int ks = 0; ks < 4; ++ks) {
      const int koff = ks * 32 + quad * 8;
      short8 afr[4], bfr[4];
      #pragma unroll
      for (int mi = 0; mi < 4; ++mi) {
        int r = wr * 64 + mi * 16 + rsel;
        afr[mi] = *(const short8*)&Xs[r * 128 + (koff ^ ((r & 7) << 3))];
      }
      #pragma unroll
      for (int ni = 0; ni < 4; ++ni) {
        int r = wc * 64 + ni * 16 + rsel;
        bfr[ni] = *(const short8*)&Ws[r * 128 + (koff ^ ((r & 7) << 3))];
      }
      #pragma unroll
      for (int mi = 0; mi < 4; ++mi)
        #pragma unroll
        for (int ni = 0; ni < 4; ++ni)
          acc[mi][ni] = __builtin_amdgcn_mfma_f32_16x16x32_bf16(afr[mi], bfr[ni], acc[mi][ni], 0, 0, 0);
    }
    #pragma unroll
    for (int mi = 0; mi < 4; ++mi)
      #pragma unroll
      for (int ni = 0; ni < 4; ++ni)
        #pragma unroll
        for (int r = 0; r < 4; ++r) {
          int pix = gpix0 + wr * 64 + mi * 16 + quad * 4 + r;
          int ch = wc * 64 + ni * 16 + rsel;
          qb[(size_t)pix * C + ch] = f2bf(acc[mi][ni][r]);
        }
  } else {
    // ---- k+v: layout B, two phases ----
    f32x4 acck[4][4], accv[4][4];
    #pragma unroll
    for (int mi = 0; mi < 4; ++mi)
      #pragma unroll
      for (int ni = 0; ni < 4; ++ni) {
        acck[mi][ni] = (f32x4){0.f, 0.f, 0.f, 0.f};
        accv[mi][ni] = (f32x4){0.f, 0.f, 0.f, 0.f};
      }
    #pragma unroll
    for (int ph = 0; ph < 2; ++ph) {
      if (ph == 1) __syncthreads();   // waves done reading Ws phase 0
      const float* wsrc = w_qkv + (size_t)(128 + ph * 128) * C;
      #pragma unroll
      for (int i = 0; i < 16; ++i) {
        int linear = i * 256 + t;
        int c4 = (linear & 31) * 4;
        int o = linear >> 5;
        float4 w4 = *(const float4*)(wsrc + (size_t)o * C + c4);
        *(unsigned long long*)&Ws[o * 128 + (c4 ^ ((o & 7) << 3))] = pk4(w4.x, w4.y, w4.z, w4.w);
      }
      __syncthreads();
      #pragma unroll
      for (int ks = 0; ks < 4; ++ks) {
        const int koff = ks * 32 + quad * 8;
        short8 afr[4], bfr[4];
        #pragma unroll
        for (int mi = 0; mi < 4; ++mi) {
          int r = wr * 64 + mi * 16 + rsel;
          afr[mi] = *(const short8*)&Ws[r * 128 + (koff ^ ((r & 7) << 3))];   // och
        }
        #pragma unroll
        for (int ni = 0; ni < 4; ++ni) {
          int r = wc * 64 + ni * 16 + rsel;
          bfr[ni] = *(const short8*)&Xs[r * 128 + (koff ^ ((r & 7) << 3))];   // pix
        }
        #pragma unroll
        for (int mi = 0; mi < 4; ++mi)
          #pragma unroll
          for (int ni = 0; ni < 4; ++ni) {
            if (ph == 0)
              acck[mi][ni] = __builtin_amdgcn_mfma_f32_16x16x32_bf16(afr[mi], bfr[ni], acck[mi][ni], 0, 0, 0);
            else
              accv[mi][ni] = __builtin_amdgcn_mfma_f32_16x16x32_bf16(afr[mi], bfr[ni], accv[mi][ni], 0, 0, 0);
          }
      }
    }
    __syncthreads();                       // all MFMA LDS reads done
    unsigned* kvs = (unsigned*)smem;       // [pix][65] dwords, 33 KB overlay
    #pragma unroll
    for (int mi = 0; mi < 4; ++mi)
      #pragma unroll
      for (int ni = 0; ni < 4; ++ni) {
        int ochb = wr * 64 + mi * 16 + quad * 4;   // even
        int pixl = wc * 64 + ni * 16 + rsel;
        unsigned d0 = (unsigned)__builtin_amdgcn_cvt_pk_fp8_f32(acck[mi][ni][0], acck[mi][ni][1], 0, false) & 0xffffu;
        d0 = (unsigned)__builtin_amdgcn_cvt_pk_fp8_f32(accv[mi][ni][0], accv[mi][ni][1], (int)d0, true);
        unsigned d1 = (unsigned)__builtin_amdgcn_cvt_pk_fp8_f32(acck[mi][ni][2], acck[mi][ni][3], 0, false) & 0xffffu;
        d1 = (unsigned)__builtin_amdgcn_cvt_pk_fp8_f32(accv[mi][ni][2], accv[mi][ni][3], (int)d1, true);
        kvs[pixl * 65 + (ochb >> 1) + 0] = d0;
        kvs[pixl * 65 + (ochb >> 1) + 1] = d1;
      }
    __syncthreads();
    #pragma unroll
    for (int i = 0; i < 32; ++i) {         // coalesced 256B dword stores
      int linear = i * 256 + t;
      int p = linear >> 6;
      int d = linear & 63;
      kvb[((size_t)(gpix0 + p)) * 64 + d] = kvs[p * 65 + d];
    }
  }
}

// ---------------- Kernel 2: fused gather + attention (fp8 kv, 1 dword/corner) -
__global__ __launch_bounds__(256) void k_attn(const unsigned short* __restrict__ qb,
                                              const unsigned* __restrict__ kvb,
                                              const int* __restrict__ psf,
                                              const float* __restrict__ pw,
                                              const int* __restrict__ pi,
                                              unsigned short* __restrict__ ao) {
  const int t = threadIdx.x;
  const int lane = t & 63;
  const int p = blockIdx.x;
  const int b = (p >> 1) & 3;                    // batch -> XCD pair
  const int j = ((p >> 3) << 1) | (p & 1);
  const int spix = __builtin_amdgcn_readfirstlane((b << 14) + (j << 2) + (t >> 6));

  const unsigned* kv32 = kvb + (size_t)b * HW * 64;  // SGPR base

  const unsigned qp = ((const unsigned*)qb)[(size_t)spix * 64 + lane];
  const float qx = bflo(qp), qy = bfhi(qp);

  int anch[16];
  #pragma unroll
  for (int jj = 0; jj < 16; ++jj) anch[jj] = psf[(size_t)spix * 16 + jj];

  float dk[8];
  float2 vs[8];
  #pragma unroll
  for (int k = 0; k < 8; ++k) {
    const int x0 = anch[k * 2 + 0] + pi[2 * k + 0], x1 = x0 + 1;  // SALU
    const int y0 = anch[k * 2 + 1] + pi[2 * k + 1], y1 = y0 + 1;
    float ksx = 0, ksy = 0, vsx = 0, vsy = 0;
    #pragma unroll
    for (int cn = 0; cn < 4; ++cn) {
      const int xi = (cn & 1) ? x1 : x0;
      const int yi = (cn & 2) ? y1 : y0;
      const bool valid = (xi >= 0) & (xi <= 127) & (yi >= 0) & (yi <= 127);
      const int xc = min(max(xi, 0), 127);
      const int yc = min(max(yi, 0), 127);
      const float wv = valid ? pw[k * 4 + cn] : 0.0f;              // scalar select
      const unsigned kv = kv32[(size_t)(yc * 128 + xc) * 64 + lane];  // 1 dword, 256B/wave
      f32x2 kp = __builtin_amdgcn_cvt_pk_f32_fp8((int)kv, false);
      f32x2 vp = __builtin_amdgcn_cvt_pk_f32_fp8((int)kv, true);
      ksx += wv * kp.x; ksy += wv * kp.y;
      vsx += wv * vp.x; vsy += wv * vp.y;
    }
    vs[k] = make_float2(vsx, vsy);
    dk[k] = qx * ksx + qy * ksy;
  }
  #pragma unroll
  for (int off = 32; off > 0; off >>= 1) {
    #pragma unroll
    for (int k = 0; k < 8; ++k) dk[k] += __shfl_xor(dk[k], off);
  }
  float lg[8];
  float m = dk[0] * 0.08838834764831845f;
  #pragma unroll
  for (int k = 0; k < 8; ++k) { lg[k] = dk[k] * 0.08838834764831845f; m = fmaxf(m, lg[k]); }
  float e[8], den = 0.0f;
  #pragma unroll
  for (int k = 0; k < 8; ++k) { e[k] = __expf(lg[k] - m); den += e[k]; }
  const float inv = 1.0f / den;
  float ox = 0, oy = 0;
  #pragma unroll
  for (int k = 0; k < 8; ++k) { float pk = e[k] * inv; ox += pk * vs[k].x; oy += pk * vs[k].y; }
  ((unsigned*)ao)[(size_t)spix * 64 + lane] = (unsigned)f2bf(ox) | ((unsigned)f2bf(oy) << 16);
}

// ---------------- Kernel 3: out = x + w_proj @ ao  (bf16 MFMA) ----------------
__global__ __launch_bounds__(256) void k_proj(const unsigned short* __restrict__ ao,
                                              const float* __restrict__ w_proj,
                                              const float* __restrict__ x,
                                              float* __restrict__ out) {
  __shared__ __align__(16) unsigned short As[128 * 128];
  __shared__ __align__(16) unsigned short Ws[128 * 128];
  const int t = threadIdx.x;
  const int gpix0 = blockIdx.x * 128;
  const int b = gpix0 >> 14;
  const int hw0 = gpix0 & (HW - 1);

  #pragma unroll
  for (int i = 0; i < 8; ++i) {
    int linear = i * 256 + t;
    int c8 = (linear & 15) * 8;
    int p = linear >> 4;
    uint4 v = *(const uint4*)(ao + (size_t)(gpix0 + p) * C + c8);
    *(uint4*)&As[p * 128 + (c8 ^ ((p & 7) << 3))] = v;
  }
  #pragma unroll
  for (int i = 0; i < 16; ++i) {
    int linear = i * 256 + t;
    int c4 = (linear & 31) * 4;
    int o = linear >> 5;
    float4 w4 = *(const float4*)(w_proj + (size_t)o * C + c4);
    *(unsigned long long*)&Ws[o * 128 + (c4 ^ ((o & 7) << 3))] = pk4(w4.x, w4.y, w4.z, w4.w);
  }
  __syncthreads();

  const int wave = t >> 6, lane = t & 63;
  const int wr = wave >> 1, wc = wave & 1;
  const int rsel = lane & 15, quad = lane >> 4;

  f32x4 acc[4][4];
  #pragma unroll
  for (int mi = 0; mi < 4; ++mi)
    #pragma unroll
    for (int ni = 0; ni < 4; ++ni) acc[mi][ni] = (f32x4){0.f, 0.f, 0.f, 0.f};

  #pragma unroll
  for (int ks = 0; ks < 4; ++ks) {
    const int koff = ks * 32 + quad * 8;
    short8 afr[4], bfr[4];
    #pragma unroll
    for (int mi = 0; mi < 4; ++mi) {
      int r = wr * 64 + mi * 16 + rsel;
      afr[mi] = *(const short8*)&Ws[r * 128 + (koff ^ ((r & 7) << 3))];
    }
    #pragma unroll
    for (int ni = 0; ni < 4; ++ni) {
      int r = wc * 64 + ni * 16 + rsel;
      bfr[ni] = *(const short8*)&As[r * 128 + (koff ^ ((r & 7) << 3))];
    }
    #pragma unroll
    for (int mi = 0; mi < 4; ++mi)
      #pragma unroll
      for (int ni = 0; ni < 4; ++ni)
        acc[mi][ni] = __builtin_amdgcn_mfma_f32_16x16x32_bf16(afr[mi], bfr[ni], acc[mi][ni], 0, 0, 0);
  }

  #pragma unroll
  for (int mi = 0; mi < 4; ++mi)
    #pragma unroll
    for (int ni = 0; ni < 4; ++ni)
      #pragma unroll
      for (int r = 0; r < 4; ++r) {
        int och = wr * 64 + mi * 16 + quad * 4 + r;
        int pixl = wc * 64 + ni * 16 + rsel;
        size_t addr = ((size_t)b * C + och) * HW + hw0 + pixl;
        out[addr] = x[addr] + acc[mi][ni][r];
      }
}

extern "C" void kernel_launch(void* const* d_in, const int* in_sizes, int n_in,
                              void* d_out, int out_size, void* d_ws, size_t ws_size,
                              hipStream_t stream) {
  const float* x      = (const float*)d_in[0];
  const int*   psf    = (const int*)d_in[1];
  const float* delta  = (const float*)d_in[2];
  const float* w_qkv  = (const float*)d_in[3];
  const float* w_proj = (const float*)d_in[4];
  float* out = (float*)d_out;

  const size_t N = (size_t)4 * HW * C;            // 8388608 elems
  unsigned short* qb = (unsigned short*)d_ws;     // 16 MB bf16 [pix][ch]
  unsigned* kvb = (unsigned*)(qb + N);            // 16 MB fp8x4 [pix][chpair]
  unsigned short* ao = (unsigned short*)(kvb + (size_t)4 * HW * 64);  // 16 MB
  float* pw = (float*)(ao + N);                   // 32 floats
  int*   pi = (int*)(pw + 32);                    // 16 ints

  k_prep<<<1, 64, 0, stream>>>(delta, pw, pi);
  k_qkv<<<dim3(512, 2), 256, 0, stream>>>(x, w_qkv, qb, kvb);
  k_attn<<<dim3(HW), 256, 0, stream>>>(qb, kvb, psf, pw, pi, ao);
  k_proj<<<dim3(512), 256, 0, stream>>>(ao, w_proj, x, out);
}

// Round 8
// 176.756 us; speedup vs baseline: 1.3090x; 1.0102x over previous
//
#include <hip/hip_runtime.h>

#define HW 16384
#define C 128

typedef __attribute__((ext_vector_type(8))) short short8;
typedef __attribute__((ext_vector_type(4))) float f32x4;
typedef __attribute__((ext_vector_type(2))) float f32x2;

__device__ __forceinline__ unsigned short f2bf(float f) {
  union { float f; unsigned u; } v; v.f = f;
  return (unsigned short)((v.u + 0x7fffu + ((v.u >> 16) & 1u)) >> 16);
}
#if __has_builtin(__builtin_amdgcn_cvt_pk_bf16_f32)
typedef __attribute__((ext_vector_type(2))) __bf16 bf16x2;
__device__ __forceinline__ unsigned pk2(float a, float b) {   // HW RNE pack
  union { bf16x2 v; unsigned u; } cv;
  cv.v = __builtin_amdgcn_cvt_pk_bf16_f32(a, b);
  return cv.u;
}
#else
__device__ __forceinline__ unsigned pk2(float a, float b) {   // SW RNE pack
  return (unsigned)f2bf(a) | ((unsigned)f2bf(b) << 16);
}
#endif
__device__ __forceinline__ unsigned short f2bf1(float a) {
  return (unsigned short)(pk2(a, a) & 0xffffu);
}
__device__ __forceinline__ float bflo(unsigned w) {
  union { unsigned u; float f; } v; v.u = w << 16; return v.f;
}
__device__ __forceinline__ float bfhi(unsigned w) {
  union { unsigned u; float f; } v; v.u = w & 0xffff0000u; return v.f;
}

// ---------------- Kernel 0: precompute bilinear weight table ------------------
__global__ void k_prep(const float* __restrict__ delta, float* __restrict__ pw,
                       int* __restrict__ pi) {
  int k = threadIdx.x;
  if (k < 8) {
    float s0 = tanhf(delta[k * 2 + 0]) * 4.0f;  // col shift (x)
    float s1 = tanhf(delta[k * 2 + 1]) * 4.0f;  // row shift (y)
    float f0 = floorf(s0), f1 = floorf(s1);
    pi[2 * k + 0] = (int)f0;
    pi[2 * k + 1] = (int)f1;
    float fx = s0 - f0, fy = s1 - f1;
    pw[4 * k + 0] = (1.0f - fx) * (1.0f - fy);
    pw[4 * k + 1] = fx * (1.0f - fy);
    pw[4 * k + 2] = (1.0f - fx) * fy;
    pw[4 * k + 3] = fx * fy;
  }
}

// ---------------- Kernel 1: qkv GEMM, merged ----------------------------------
// One block per 128-pix tile. X staged once; three W phases:
//   q  (layout A: D row=pix, col=och) -> qb bf16 [pix][ch]
//   k,v(layout B: D row=och, col=pix) -> packed fp8 [k0,k1,v0,v1]/dword -> kvb
__global__ __launch_bounds__(256) void k_qkv(const float* __restrict__ x,
                                             const float* __restrict__ w_qkv,
                                             unsigned short* __restrict__ qb,
                                             unsigned* __restrict__ kvb) {
  __shared__ __align__(16) unsigned char smem[66560];
  unsigned short* Xs = (unsigned short*)smem;            // [pix][k] 32 KB
  unsigned short* Ws = (unsigned short*)(smem + 32768);  // [och][k] 32 KB
  const int t = threadIdx.x;
  const int gpix0 = blockIdx.x * 128;
  const int b = gpix0 >> 14;
  const int hw0 = gpix0 & (HW - 1);

  // stage Xs [pix][k] bf16, xor-swizzled (HW cvt)
  const float* xb = x + (size_t)b * C * HW + hw0;
  #pragma unroll
  for (int i = 0; i < 16; ++i) {
    int linear = i * 256 + t;
    int p = linear & 127;
    int c4 = (linear >> 7) * 4;
    float a0 = xb[(size_t)(c4 + 0) * HW + p];
    float a1 = xb[(size_t)(c4 + 1) * HW + p];
    float a2 = xb[(size_t)(c4 + 2) * HW + p];
    float a3 = xb[(size_t)(c4 + 3) * HW + p];
    int cc = c4 ^ ((p & 7) << 3);
    *(uint2*)&Xs[p * 128 + cc] = make_uint2(pk2(a0, a1), pk2(a2, a3));
  }

  const int wave = t >> 6, lane = t & 63;
  const int wr = wave >> 1, wc = wave & 1;
  const int rsel = lane & 15, quad = lane >> 4;

  // ---- phase q: stage Wq, MFMA layout A ----
  #pragma unroll
  for (int i = 0; i < 16; ++i) {
    int linear = i * 256 + t;
    int c4 = (linear & 31) * 4;
    int o = linear >> 5;
    float4 w4 = *(const float4*)(w_qkv + (size_t)o * C + c4);
    *(uint2*)&Ws[o * 128 + (c4 ^ ((o & 7) << 3))] = make_uint2(pk2(w4.x, w4.y), pk2(w4.z, w4.w));
  }
  __syncthreads();
  {
    f32x4 acc[4][4];
    #pragma unroll
    for (int mi = 0; mi < 4; ++mi)
      #pragma unroll
      for (int ni = 0; ni < 4; ++ni) acc[mi][ni] = (f32x4){0.f, 0.f, 0.f, 0.f};
    #pragma unroll
    for (int ks = 0; ks < 4; ++ks) {
      const int koff = ks * 32 + quad * 8;
      short8 afr[4], bfr[4];
      #pragma unroll
      for (int mi = 0; mi < 4; ++mi) {
        int r = wr * 64 + mi * 16 + rsel;
        afr[mi] = *(const short8*)&Xs[r * 128 + (koff ^ ((r & 7) << 3))];
      }
      #pragma unroll
      for (int ni = 0; ni < 4; ++ni) {
        int r = wc * 64 + ni * 16 + rsel;
        bfr[ni] = *(const short8*)&Ws[r * 128 + (koff ^ ((r & 7) << 3))];
      }
      #pragma unroll
      for (int mi = 0; mi < 4; ++mi)
        #pragma unroll
        for (int ni = 0; ni < 4; ++ni)
          acc[mi][ni] = __builtin_amdgcn_mfma_f32_16x16x32_bf16(afr[mi], bfr[ni], acc[mi][ni], 0, 0, 0);
    }
    #pragma unroll
    for (int mi = 0; mi < 4; ++mi)
      #pragma unroll
      for (int ni = 0; ni < 4; ++ni)
        #pragma unroll
        for (int r = 0; r < 4; ++r) {
          int pix = gpix0 + wr * 64 + mi * 16 + quad * 4 + r;
          int ch = wc * 64 + ni * 16 + rsel;
          qb[(size_t)pix * C + ch] = f2bf1(acc[mi][ni][r]);
        }
  }

  // ---- phases k,v: layout B ----
  f32x4 acck[4][4], accv[4][4];
  #pragma unroll
  for (int mi = 0; mi < 4; ++mi)
    #pragma unroll
    for (int ni = 0; ni < 4; ++ni) {
      acck[mi][ni] = (f32x4){0.f, 0.f, 0.f, 0.f};
      accv[mi][ni] = (f32x4){0.f, 0.f, 0.f, 0.f};
    }
  #pragma unroll
  for (int ph = 0; ph < 2; ++ph) {
    __syncthreads();   // previous phase's Ws reads done
    const float* wsrc = w_qkv + (size_t)(128 + ph * 128) * C;
    #pragma unroll
    for (int i = 0; i < 16; ++i) {
      int linear = i * 256 + t;
      int c4 = (linear & 31) * 4;
      int o = linear >> 5;
      float4 w4 = *(const float4*)(wsrc + (size_t)o * C + c4);
      *(uint2*)&Ws[o * 128 + (c4 ^ ((o & 7) << 3))] = make_uint2(pk2(w4.x, w4.y), pk2(w4.z, w4.w));
    }
    __syncthreads();
    #pragma unroll
    for (int ks = 0; ks < 4; ++ks) {
      const int koff = ks * 32 + quad * 8;
      short8 afr[4], bfr[4];
      #pragma unroll
      for (int mi = 0; mi < 4; ++mi) {
        int r = wr * 64 + mi * 16 + rsel;
        afr[mi] = *(const short8*)&Ws[r * 128 + (koff ^ ((r & 7) << 3))];   // och
      }
      #pragma unroll
      for (int ni = 0; ni < 4; ++ni) {
        int r = wc * 64 + ni * 16 + rsel;
        bfr[ni] = *(const short8*)&Xs[r * 128 + (koff ^ ((r & 7) << 3))];   // pix
      }
      #pragma unroll
      for (int mi = 0; mi < 4; ++mi)
        #pragma unroll
        for (int ni = 0; ni < 4; ++ni) {
          if (ph == 0)
            acck[mi][ni] = __builtin_amdgcn_mfma_f32_16x16x32_bf16(afr[mi], bfr[ni], acck[mi][ni], 0, 0, 0);
          else
            accv[mi][ni] = __builtin_amdgcn_mfma_f32_16x16x32_bf16(afr[mi], bfr[ni], accv[mi][ni], 0, 0, 0);
        }
    }
  }
  __syncthreads();                       // all MFMA LDS reads done
  unsigned* kvs = (unsigned*)smem;       // [pix][65] dwords overlay (33 KB)
  #pragma unroll
  for (int mi = 0; mi < 4; ++mi)
    #pragma unroll
    for (int ni = 0; ni < 4; ++ni) {
      int ochb = wr * 64 + mi * 16 + quad * 4;   // even
      int pixl = wc * 64 + ni * 16 + rsel;
      unsigned d0 = (unsigned)__builtin_amdgcn_cvt_pk_fp8_f32(acck[mi][ni][0], acck[mi][ni][1], 0, false) & 0xffffu;
      d0 = (unsigned)__builtin_amdgcn_cvt_pk_fp8_f32(accv[mi][ni][0], accv[mi][ni][1], (int)d0, true);
      unsigned d1 = (unsigned)__builtin_amdgcn_cvt_pk_fp8_f32(acck[mi][ni][2], acck[mi][ni][3], 0, false) & 0xffffu;
      d1 = (unsigned)__builtin_amdgcn_cvt_pk_fp8_f32(accv[mi][ni][2], accv[mi][ni][3], (int)d1, true);
      kvs[pixl * 65 + (ochb >> 1) + 0] = d0;
      kvs[pixl * 65 + (ochb >> 1) + 1] = d1;
    }
  __syncthreads();
  #pragma unroll
  for (int i = 0; i < 32; ++i) {         // coalesced 256B dword stores
    int linear = i * 256 + t;
    int p = linear >> 6;
    int d = linear & 63;
    kvb[((size_t)(gpix0 + p)) * 64 + d] = kvs[p * 65 + d];
  }
}

// ---------------- Kernel 2: fused gather + attention (fp8 kv, 1 dword/corner) -
__global__ __launch_bounds__(256) void k_attn(const unsigned short* __restrict__ qb,
                                              const unsigned* __restrict__ kvb,
                                              const int* __restrict__ psf,
                                              const float* __restrict__ pw,
                                              const int* __restrict__ pi,
                                              unsigned short* __restrict__ ao) {
  const int t = threadIdx.x;
  const int lane = t & 63;
  const int p = blockIdx.x;
  const int b = (p >> 1) & 3;                    // batch -> XCD pair
  const int j = ((p >> 3) << 1) | (p & 1);
  const int spix = __builtin_amdgcn_readfirstlane((b << 14) + (j << 2) + (t >> 6));

  const unsigned* kv32 = kvb + (size_t)b * HW * 64;  // SGPR base

  const unsigned qp = ((const unsigned*)qb)[(size_t)spix * 64 + lane];
  const float qx = bflo(qp), qy = bfhi(qp);

  int anch[16];
  #pragma unroll
  for (int jj = 0; jj < 16; ++jj) anch[jj] = psf[(size_t)spix * 16 + jj];

  float dk[8];
  float2 vs[8];
  #pragma unroll
  for (int k = 0; k < 8; ++k) {
    const int x0 = anch[k * 2 + 0] + pi[2 * k + 0], x1 = x0 + 1;  // SALU
    const int y0 = anch[k * 2 + 1] + pi[2 * k + 1], y1 = y0 + 1;
    float ksx = 0, ksy = 0, vsx = 0, vsy = 0;
    #pragma unroll
    for (int cn = 0; cn < 4; ++cn) {
      const int xi = (cn & 1) ? x1 : x0;
      const int yi = (cn & 2) ? y1 : y0;
      const bool valid = (xi >= 0) & (xi <= 127) & (yi >= 0) & (yi <= 127);
      const int xc = min(max(xi, 0), 127);
      const int yc = min(max(yi, 0), 127);
      const float wv = valid ? pw[k * 4 + cn] : 0.0f;              // scalar select
      const unsigned kv = kv32[(size_t)(yc * 128 + xc) * 64 + lane];  // 1 dword/corner
      f32x2 kp = __builtin_amdgcn_cvt_pk_f32_fp8((int)kv, false);
      f32x2 vp = __builtin_amdgcn_cvt_pk_f32_fp8((int)kv, true);
      ksx += wv * kp.x; ksy += wv * kp.y;
      vsx += wv * vp.x; vsy += wv * vp.y;
    }
    vs[k] = make_float2(vsx, vsy);
    dk[k] = qx * ksx + qy * ksy;
  }
  #pragma unroll
  for (int off = 32; off > 0; off >>= 1) {
    #pragma unroll
    for (int k = 0; k < 8; ++k) dk[k] += __shfl_xor(dk[k], off);
  }
  float lg[8];
  float m = dk[0] * 0.08838834764831845f;
  #pragma unroll
  for (int k = 0; k < 8; ++k) { lg[k] = dk[k] * 0.08838834764831845f; m = fmaxf(m, lg[k]); }
  float e[8], den = 0.0f;
  #pragma unroll
  for (int k = 0; k < 8; ++k) { e[k] = __expf(lg[k] - m); den += e[k]; }
  const float inv = 1.0f / den;
  float ox = 0, oy = 0;
  #pragma unroll
  for (int k = 0; k < 8; ++k) { float pk = e[k] * inv; ox += pk * vs[k].x; oy += pk * vs[k].y; }
  ((unsigned*)ao)[(size_t)spix * 64 + lane] = pk2(ox, oy);
}

// ---------------- Kernel 3: out = x + w_proj @ ao  (bf16 MFMA) ----------------
__global__ __launch_bounds__(256) void k_proj(const unsigned short* __restrict__ ao,
                                              const float* __restrict__ w_proj,
                                              const float* __restrict__ x,
                                              float* __restrict__ out) {
  __shared__ __align__(16) unsigned short As[128 * 128];
  __shared__ __align__(16) unsigned short Ws[128 * 128];
  const int t = threadIdx.x;
  const int gpix0 = blockIdx.x * 128;
  const int b = gpix0 >> 14;
  const int hw0 = gpix0 & (HW - 1);

  #pragma unroll
  for (int i = 0; i < 8; ++i) {
    int linear = i * 256 + t;
    int c8 = (linear & 15) * 8;
    int p = linear >> 4;
    uint4 v = *(const uint4*)(ao + (size_t)(gpix0 + p) * C + c8);
    *(uint4*)&As[p * 128 + (c8 ^ ((p & 7) << 3))] = v;
  }
  #pragma unroll
  for (int i = 0; i < 16; ++i) {
    int linear = i * 256 + t;
    int c4 = (linear & 31) * 4;
    int o = linear >> 5;
    float4 w4 = *(const float4*)(w_proj + (size_t)o * C + c4);
    *(uint2*)&Ws[o * 128 + (c4 ^ ((o & 7) << 3))] = make_uint2(pk2(w4.x, w4.y), pk2(w4.z, w4.w));
  }
  __syncthreads();

  const int wave = t >> 6, lane = t & 63;
  const int wr = wave >> 1, wc = wave & 1;
  const int rsel = lane & 15, quad = lane >> 4;

  f32x4 acc[4][4];
  #pragma unroll
  for (int mi = 0; mi < 4; ++mi)
    #pragma unroll
    for (int ni = 0; ni < 4; ++ni) acc[mi][ni] = (f32x4){0.f, 0.f, 0.f, 0.f};

  #pragma unroll
  for (int ks = 0; ks < 4; ++ks) {
    const int koff = ks * 32 + quad * 8;
    short8 afr[4], bfr[4];
    #pragma unroll
    for (int mi = 0; mi < 4; ++mi) {
      int r = wr * 64 + mi * 16 + rsel;
      afr[mi] = *(const short8*)&Ws[r * 128 + (koff ^ ((r & 7) << 3))];
    }
    #pragma unroll
    for (int ni = 0; ni < 4; ++ni) {
      int r = wc * 64 + ni * 16 + rsel;
      bfr[ni] = *(const short8*)&As[r * 128 + (koff ^ ((r & 7) << 3))];
    }
    #pragma unroll
    for (int mi = 0; mi < 4; ++mi)
      #pragma unroll
      for (int ni = 0; ni < 4; ++ni)
        acc[mi][ni] = __builtin_amdgcn_mfma_f32_16x16x32_bf16(afr[mi], bfr[ni], acc[mi][ni], 0, 0, 0);
  }

  #pragma unroll
  for (int mi = 0; mi < 4; ++mi)
    #pragma unroll
    for (int ni = 0; ni < 4; ++ni)
      #pragma unroll
      for (int r = 0; r < 4; ++r) {
        int och = wr * 64 + mi * 16 + quad * 4 + r;
        int pixl = wc * 64 + ni * 16 + rsel;
        size_t addr = ((size_t)b * C + och) * HW + hw0 + pixl;
        out[addr] = x[addr] + acc[mi][ni][r];
      }
}

extern "C" void kernel_launch(void* const* d_in, const int* in_sizes, int n_in,
                              void* d_out, int out_size, void* d_ws, size_t ws_size,
                              hipStream_t stream) {
  const float* x      = (const float*)d_in[0];
  const int*   psf    = (const int*)d_in[1];
  const float* delta  = (const float*)d_in[2];
  const float* w_qkv  = (const float*)d_in[3];
  const float* w_proj = (const float*)d_in[4];
  float* out = (float*)d_out;

  const size_t N = (size_t)4 * HW * C;            // 8388608 elems
  unsigned short* qb = (unsigned short*)d_ws;     // 16 MB bf16 [pix][ch]
  unsigned* kvb = (unsigned*)(qb + N);            // 16 MB fp8x4 [pix][chpair]
  unsigned short* ao = (unsigned short*)(kvb + (size_t)4 * HW * 64);  // 16 MB
  float* pw = (float*)(ao + N);                   // 32 floats
  int*   pi = (int*)(pw + 32);                    // 16 ints

  k_prep<<<1, 64, 0, stream>>>(delta, pw, pi);
  k_qkv<<<dim3(512), 256, 0, stream>>>(x, w_qkv, qb, kvb);
  k_attn<<<dim3(HW), 256, 0, stream>>>(qb, kvb, psf, pw, pi, ao);
  k_proj<<<dim3(512), 256, 0, stream>>>(ao, w_proj, x, out);
}